// Round 4
// baseline (1456.379 us; speedup 1.0000x reference)
//
#include <hip/hip_runtime.h>
#include <hip/hip_cooperative_groups.h>

namespace cg = cooperative_groups;

// Problem constants (fixed by the reference)
#define NL 48     // dialogue length
#define ND 256    // global feature dim
#define NH 256    // rgcn dim
#define NG 256    // gcn dim
#define NA 128    // attention dim

// Single cooperative kernel: all 5 dependent stages fused with grid.sync().
// grid = 192 blocks (>= all work shapes), block = 256, 1 block/CU -> trivially
// co-resident (192 <= 256 CUs), static LDS 2 KiB.
//
// Phase 1: y[i][c] = x[i] @ W_rel[rid(i,c)]   (all 192 blocks, i=b>>2, c=b&3)
//          q,k = x @ Wq / x @ Wk              (blocks 0..47 additionally)
// Phase 2: attn row-softmax of v.tanh(q_i + k_j)  (blocks 0..47, wave 0)
// Phase 3: h[j] = sum_i attn[i][j]*y[i][c(i,j)] + x[j]@W_root + b   (blocks 0..47)
// Phase 4: out[j] = h[j]@W_self + (sum_j h[j])@W_nbr + b            (blocks 0..47;
//          sumh recomputed per block: 48 L2-hit loads/thread, cheaper than a launch)
__global__ void __launch_bounds__(256, 1) fused_dialoguegcn(
    const float* __restrict__ x,      const int* __restrict__ speaker,
    const float* __restrict__ Wq,     const float* __restrict__ Wk,
    const float* __restrict__ v,      const float* __restrict__ W_rel,
    const float* __restrict__ W_root, const float* __restrict__ b_rgcn,
    const float* __restrict__ W_nbr,  const float* __restrict__ W_self,
    const float* __restrict__ b_gcn,
    float* __restrict__ q, float* __restrict__ k, float* __restrict__ attn,
    float* __restrict__ y, float* __restrict__ h, float* __restrict__ out)
{
    cg::grid_group grid = cg::this_grid();
    const int b = blockIdx.x;      // 0..191
    const int t = threadIdx.x;     // 0..255
    __shared__ float smem[2 * ND]; // 512 floats, reused across phases

    // ---------------- Phase 1: y (all blocks) + qk (blocks < 48) ----------------
    {
        const int i = b >> 2;
        const int c = b & 3;                    // c = s_dst*2 + dir
        float* xs = smem;                       // x[i] for the y-GEMV
        float* xq = smem + ND;                  // x[b] for the qk-GEMV
        xs[t] = x[i * ND + t];
        if (b < NL) xq[t] = x[b * ND + t];
        __syncthreads();

        const int rid = 2 * (speaker[i] * NL + (c >> 1)) + (c & 1);
        const float* W = W_rel + (size_t)rid * ND * NH;
        float acc = 0.f;
        #pragma unroll 8
        for (int d = 0; d < ND; ++d)
            acc += xs[d] * W[d * NH + t];
        y[(i * 4 + c) * NH + t] = acc;

        if (b < NL) {
            // waves 0-1 (t<128) compute q-cols, waves 2-3 compute k-cols
            const float* Wqk = (t < NA) ? Wq : Wk;
            const int a = t & (NA - 1);
            float accq = 0.f;
            #pragma unroll 8
            for (int d = 0; d < ND; ++d)
                accq += xq[d] * Wqk[d * NA + a];
            float* qk = (t < NA) ? q : k;
            qk[b * NA + a] = accq;
        }
    }
    grid.sync();

    // ---------------- Phase 2: attention softmax (blocks < 48, wave 0) ----------
    if (b < NL && t < 64) {
        const int i = b, j = t;                 // j < 48 active
        float* qs = smem;                       // q row i
        float* vs = smem + NA;
        qs[j]      = q[i * NA + j];
        qs[j + 64] = q[i * NA + j + 64];
        vs[j]      = v[j];
        vs[j + 64] = v[j + 64];
        // single-wave LDS producer/consumer: lockstep, compiler inserts lgkmcnt

        float s = -INFINITY;
        if (j < NL) {
            float sc = 0.f;
            #pragma unroll 8
            for (int a = 0; a < NA; ++a)
                sc += vs[a] * tanhf(qs[a] + k[j * NA + a]);
            s = sc;
        }
        float m = s;
        for (int off = 32; off; off >>= 1) m = fmaxf(m, __shfl_xor(m, off));
        float e = (j < NL) ? __expf(s - m) : 0.f;
        float tot = e;
        for (int off = 32; off; off >>= 1) tot += __shfl_xor(tot, off);
        if (j < NL) attn[i * NL + j] = e / tot;
    }
    grid.sync();

    // ---------------- Phase 3: h rows (blocks < 48) ------------------------------
    if (b < NL) {
        const int j = b;
        float* xs   = smem;                     // x[j]
        float* wcol = smem + ND;                // attn[:, j]
        xs[t] = x[j * ND + t];
        if (t < NL) wcol[t] = attn[t * NL + j];
        __syncthreads();

        const int sj = speaker[j];
        float acc = b_rgcn[t];
        for (int i = 0; i < NL; ++i) {
            const int c = sj * 2 + ((i < j) ? 0 : 1);
            acc += wcol[i] * y[(i * 4 + c) * NH + t];
        }
        #pragma unroll 8
        for (int d = 0; d < ND; ++d)
            acc += xs[d] * W_root[d * NH + t];
        h[j * NH + t] = acc;
    }
    grid.sync();

    // ---------------- Phase 4: sumh + out rows (blocks < 48) ---------------------
    if (b < NL) {
        const int j = b;
        float* hs = smem;                       // h[j]
        float* ss = smem + NH;                  // sum_j h[j]
        hs[t] = h[j * NH + t];
        float s = 0.f;
        #pragma unroll
        for (int jj = 0; jj < NL; ++jj) s += h[jj * NH + t];
        ss[t] = s;
        __syncthreads();

        float acc = b_gcn[t];
        #pragma unroll 8
        for (int d = 0; d < NH; ++d) {
            acc += hs[d] * W_self[d * NG + t];
            acc += ss[d] * W_nbr[d * NG + t];
        }
        out[j * NG + t] = acc;
    }
}

// ---------------------------------------------------------------------------
extern "C" void kernel_launch(void* const* d_in, const int* in_sizes, int n_in,
                              void* d_out, int out_size, void* d_ws, size_t ws_size,
                              hipStream_t stream) {
    const float* x      = (const float*)d_in[0];
    const int*   speaker= (const int*)d_in[1];
    const float* Wq     = (const float*)d_in[2];
    const float* Wk     = (const float*)d_in[3];
    const float* v      = (const float*)d_in[4];
    const float* W_rel  = (const float*)d_in[5];
    const float* W_root = (const float*)d_in[6];
    const float* b_rgcn = (const float*)d_in[7];
    const float* W_nbr  = (const float*)d_in[8];
    const float* W_self = (const float*)d_in[9];
    const float* b_gcn  = (const float*)d_in[10];
    float* out = (float*)d_out;

    // workspace layout (fp32)
    float* ws   = (float*)d_ws;
    float* q    = ws;                  // 48*128
    float* k    = q    + NL * NA;      // 48*128
    float* attn = k    + NL * NA;      // 48*48
    float* y    = attn + NL * NL;      // 48*4*256
    float* h    = y    + NL * 4 * NH;  // 48*256

    void* args[] = {
        (void*)&x, (void*)&speaker, (void*)&Wq, (void*)&Wk, (void*)&v,
        (void*)&W_rel, (void*)&W_root, (void*)&b_rgcn, (void*)&W_nbr,
        (void*)&W_self, (void*)&b_gcn,
        (void*)&q, (void*)&k, (void*)&attn, (void*)&y, (void*)&h, (void*)&out
    };
    hipLaunchCooperativeKernel((void*)fused_dialoguegcn,
                               dim3(192), dim3(256), args, 0, stream);
}